// Round 4
// baseline (248.325 us; speedup 1.0000x reference)
//
#include <hip/hip_runtime.h>
#include <hip/hip_bf16.h>
#include <math.h>

typedef __bf16 bf16_t;
typedef __attribute__((ext_vector_type(8))) __bf16 bf16x8;
typedef __attribute__((ext_vector_type(4))) __bf16 bf16x4;
typedef __attribute__((ext_vector_type(4))) float f32x4;

#define BATCH 8
#define NTOK 1024
#define DMODEL 256
#define NHEAD 8
#define HDIM 32
#define FFDIM 1024
#define NEDGE 16384
#define CAP 96   // max neighbors per row (deg ~ Poisson(32); P(deg>96) < 1e-20)

// ---------------- async global->LDS (16B per lane, wave-uniform LDS base) ----------------
__device__ __forceinline__ void gload_lds16(const void* g, void* l) {
  __builtin_amdgcn_global_load_lds(
      (const __attribute__((address_space(1))) unsigned int*)(uintptr_t)g,
      (__attribute__((address_space(3))) unsigned int*)(unsigned int)(uintptr_t)l,
      16, 0, 0);
}

// ---------------- fused: zero prio (blocks 0..2047) + f32->bf16 cvt (blocks 2048..5631) ----------------
__global__ void k_pre(int4* __restrict__ prio,
                      const float* __restrict__ H, const float* __restrict__ Wqkv,
                      const float* __restrict__ Wo, const float* __restrict__ W1,
                      const float* __restrict__ W2, bf16_t* __restrict__ xb,
                      bf16_t* __restrict__ wqkvb, bf16_t* __restrict__ wob,
                      bf16_t* __restrict__ w1b, bf16_t* __restrict__ w2b) {
  if (blockIdx.x < 2048) {
    int i = blockIdx.x * 256 + threadIdx.x;
    int4 z = {0, 0, 0, 0};
#pragma unroll
    for (int u = 0; u < 4; ++u) p_store: ;
#pragma unroll
    for (int u = 0; u < 4; ++u) prio[i + u * 524288] = z;   // 2048*256*4 = 2M int4 * 4 = 8M int4
    return;
  }
  int i = (blockIdx.x - 2048) * 256 + threadIdx.x;   // float4-quad index
  const float* s; bf16_t* d; int off;
  if (i < 524288)      { s = H;    d = xb;    off = i; }
  else if (i < 622592) { s = Wqkv; d = wqkvb; off = i - 524288; }
  else if (i < 655360) { s = Wo;   d = wob;   off = i - 622592; }
  else if (i < 786432) { s = W1;   d = w1b;   off = i - 655360; }
  else if (i < 917504) { s = W2;   d = w2b;   off = i - 786432; }
  else return;
  float4 v = ((const float4*)s)[off];
  bf16x4 o;
  o[0] = (bf16_t)v.x; o[1] = (bf16_t)v.y; o[2] = (bf16_t)v.z; o[3] = (bf16_t)v.w;
  ((bf16x4*)d)[off] = o;
}

// ---------------- bias scatter: priority = scatter order (last write wins) ----------------
__global__ void k_scatter(const int* __restrict__ ei, int* __restrict__ prio) {
  int idx = blockIdx.x * 256 + threadIdx.x;
  if (idx >= BATCH * NEDGE) return;
  int b = idx >> 14;            // / NEDGE
  int e = idx & (NEDGE - 1);
  const int* eb = ei + (size_t)b * 2 * NEDGE;
  int r = eb[e], c = eb[NEDGE + e];
  int base = b << 20;           // * NTOK*NTOK
  atomicMax(prio + base + (r << 10) + c, e + 1);           // first scatter set
  atomicMax(prio + base + (c << 10) + r, NEDGE + e + 1);   // second scatter set (wins)
}

// ---------------- CSR build: one wave per row, deterministic ballot compaction ----------------
__global__ __launch_bounds__(256) void k_build_csr(
    const int* __restrict__ prio, const float* __restrict__ mptr,
    int* __restrict__ nbcol, float* __restrict__ nbval, int* __restrict__ nbcnt) {
  int row = blockIdx.x * 4 + (threadIdx.x >> 6);   // b*1024 + i
  int l = threadIdx.x & 63;
  int i = row & 1023;
  int b = row >> 10;
  int base = 0;
  for (int it = 0; it < 16; ++it) {
    int j = it * 64 + l;
    int p = prio[((size_t)row << 10) + j];
    bool hit = (p > 0) || (j == i);
    unsigned long long mask = __ballot(hit);
    int pos = base + __popcll(mask & ((1ull << l) - 1ull));
    if (hit && pos < CAP) {
      float v = 0.f;
      if (p > 0) {
        int e = (p - 1) & (NEDGE - 1);
        v = logf(mptr[(size_t)b * NEDGE + e] + 1e-9f);
      }
      nbcol[(size_t)row * CAP + pos] = j;
      nbval[(size_t)row * CAP + pos] = v;
    }
    base += __popcll(mask);
  }
  if (l == 0) nbcnt[row] = min(base, CAP);
}

// ---------------- GEMM 128x128: C[M,N] = A[M,K] * B[N,K]^T + bias ----------------
// EPI 1: gelu -> bf16 out. EPI 2 (qkv): col<256 -> f32 qf[M][256], col>=256 -> bf16 kvb[M][512].
template <int EPI>
__global__ __launch_bounds__(256) void gemm_bt(
    const bf16_t* __restrict__ A, const bf16_t* __restrict__ Bw,
    const float* __restrict__ bias, float* __restrict__ Cf, bf16_t* __restrict__ Cb,
    int M, int N, int K) {
  __shared__ bf16_t As[128 * 64];
  __shared__ bf16_t Bs[128 * 64];
  const int t = threadIdx.x;
  const int l = t & 63;
  const int w = t >> 6;
  const int wr = w >> 1, wc = w & 1;
  const int bm = blockIdx.y * 128, bn = blockIdx.x * 128;

  f32x4 acc[4][4] = {};

  for (int k0 = 0; k0 < K; k0 += 64) {
#pragma unroll
    for (int i = 0; i < 4; ++i) {
      int idx = i * 2048 + t * 8;      // element within [128][64] tile
      int row = idx >> 6;
      int col = idx & 63;
      gload_lds16(A + (size_t)(bm + row) * K + (k0 + col), (void*)(As + i * 2048 + w * 512));
      gload_lds16(Bw + (size_t)(bn + row) * K + (k0 + col), (void*)(Bs + i * 2048 + w * 512));
    }
    asm volatile("s_waitcnt vmcnt(0)" ::: "memory");
    __syncthreads();
#pragma unroll
    for (int kk = 0; kk < 2; ++kk) {
      bf16x8 af[4], bfr[4];
#pragma unroll
      for (int mi = 0; mi < 4; ++mi)
        af[mi] = *(const bf16x8*)(As + (wr * 64 + mi * 16 + (l & 15)) * 64 + kk * 32 + (l >> 4) * 8);
#pragma unroll
      for (int ni = 0; ni < 4; ++ni)
        bfr[ni] = *(const bf16x8*)(Bs + (wc * 64 + ni * 16 + (l & 15)) * 64 + kk * 32 + (l >> 4) * 8);
#pragma unroll
      for (int mi = 0; mi < 4; ++mi)
#pragma unroll
        for (int ni = 0; ni < 4; ++ni)
          acc[mi][ni] = __builtin_amdgcn_mfma_f32_16x16x32_bf16(af[mi], bfr[ni], acc[mi][ni], 0, 0, 0);
    }
    __syncthreads();
  }

  const int r0 = (l >> 4) * 4;   // C/D: row=(lane>>4)*4+reg, col=lane&15
  const int cc = l & 15;
#pragma unroll
  for (int mi = 0; mi < 4; ++mi) {
#pragma unroll
    for (int ni = 0; ni < 4; ++ni) {
      int col = bn + wc * 64 + ni * 16 + cc;
      float bv = bias[col];
#pragma unroll
      for (int r = 0; r < 4; ++r) {
        int row = bm + wr * 64 + mi * 16 + r0 + r;
        float v = acc[mi][ni][r] + bv;
        if (EPI == 1) {
          v = 0.5f * v * (1.f + erff(v * 0.70710678118654752f));   // exact GELU
          Cb[(size_t)row * N + col] = (bf16_t)v;
        } else if (EPI == 2) {
          if (col < 256) Cf[(size_t)row * 256 + col] = v;          // q, f32
          else Cb[(size_t)row * 512 + (col - 256)] = (bf16_t)v;    // k|v, bf16 packed
        } else {
          Cf[(size_t)row * N + col] = v;
        }
      }
    }
  }
}

// ---------------- fused GEMM(BM=32, BN=256 full row) + bias + residual + LayerNorm ----------------
// y = LN(resid + A@Bw^T + bias); writes y as f32 (xfout) and bf16 (xbout).
__global__ __launch_bounds__(256) void gemm_ln(
    const bf16_t* __restrict__ A, const bf16_t* __restrict__ Bw,
    const float* __restrict__ bias, const float* __restrict__ resid,
    const float* __restrict__ lnw, const float* __restrict__ lnb,
    float* __restrict__ xfout, bf16_t* __restrict__ xbout, int K) {
  __shared__ __align__(16) char smem[36864];
  bf16_t* As = (bf16_t*)smem;            // [32][64]
  bf16_t* Bs = (bf16_t*)(smem + 4096);   // [256][64]
  float*  E  = (float*)smem;             // epi: [32][258] f32 (aliases As/Bs after barrier)
  const int t = threadIdx.x;
  const int l = t & 63;
  const int w = t >> 6;
  const int bm = blockIdx.x * 32;

  f32x4 acc[2][4] = {};

  for (int k0 = 0; k0 < K; k0 += 64) {
    {  // A tile: 32x64 = 1 issue per wave
      int e = w * 512 + l * 8;
      int row = e >> 6, col = e & 63;
      gload_lds16(A + (size_t)(bm + row) * K + (k0 + col), (void*)(As + w * 512));
    }
#pragma unroll
    for (int i = 0; i < 8; ++i) {  // B tile: 256x64 = 8 issues per wave
      int e = i * 2048 + w * 512 + l * 8;
      int row = e >> 6, col = e & 63;
      gload_lds16(Bw + (size_t)row * K + (k0 + col), (void*)(Bs + i * 2048 + w * 512));
    }
    asm volatile("s_waitcnt vmcnt(0)" ::: "memory");
    __syncthreads();
#pragma unroll
    for (int kk = 0; kk < 2; ++kk) {
      bf16x8 af[2], bfr[4];
#pragma unroll
      for (int mi = 0; mi < 2; ++mi)
        af[mi] = *(const bf16x8*)(As + (mi * 16 + (l & 15)) * 64 + kk * 32 + (l >> 4) * 8);
#pragma unroll
      for (int ni = 0; ni < 4; ++ni)
        bfr[ni] = *(const bf16x8*)(Bs + (w * 64 + ni * 16 + (l & 15)) * 64 + kk * 32 + (l >> 4) * 8);
#pragma unroll
      for (int mi = 0; mi < 2; ++mi)
#pragma unroll
        for (int ni = 0; ni < 4; ++ni)
          acc[mi][ni] = __builtin_amdgcn_mfma_f32_16x16x32_bf16(af[mi], bfr[ni], acc[mi][ni], 0, 0, 0);
    }
    __syncthreads();
  }

  // stash C+bias into LDS f32 [32][258]
  const int r0 = (l >> 4) * 4;
  const int cc = l & 15;
#pragma unroll
  for (int mi = 0; mi < 2; ++mi) {
#pragma unroll
    for (int ni = 0; ni < 4; ++ni) {
      int col = w * 64 + ni * 16 + cc;
      float bv = bias[col];
#pragma unroll
      for (int r = 0; r < 4; ++r)
        E[(mi * 16 + r0 + r) * 258 + col] = acc[mi][ni][r] + bv;
    }
  }
  __syncthreads();

  // LN: row = w*8 + (l&7), 8 lanes/row (sub = l>>3), 32 cols/lane
  const int row = w * 8 + (l & 7);
  const int sub = l >> 3;
  const float* ep = E + row * 258 + sub * 32;
  const float* rp = resid + (size_t)(bm + row) * 256 + sub * 32;
  float v[32];
  float s = 0.f;
#pragma unroll
  for (int j = 0; j < 8; ++j) {
    float4 a4 = ((const float4*)ep)[j];
    float4 b4 = ((const float4*)rp)[j];
    v[j * 4 + 0] = a4.x + b4.x; v[j * 4 + 1] = a4.y + b4.y;
    v[j * 4 + 2] = a4.z + b4.z; v[j * 4 + 3] = a4.w + b4.w;
    s += v[j * 4 + 0] + v[j * 4 + 1] + v[j * 4 + 2] + v[j * 4 + 3];
  }
#pragma unroll
  for (int o = 8; o < 64; o <<= 1) s += __shfl_xor(s, o);
  float mu = s * (1.f / 256.f);
  float e2 = 0.f;
#pragma unroll
  for (int j = 0; j < 32; ++j) { float d = v[j] - mu; e2 += d * d; }
#pragma unroll
  for (int o = 8; o < 64; o <<= 1) e2 += __shfl_xor(e2, o);
  float rs = rsqrtf(e2 * (1.f / 256.f) + 1e-5f);
  float* xo = xfout + (size_t)(bm + row) * 256 + sub * 32;
  bf16_t* xbo = xbout + (size_t)(bm + row) * 256 + sub * 32;
#pragma unroll
  for (int j = 0; j < 8; ++j) {
    float4 w4 = ((const float4*)(lnw + sub * 32))[j];
    float4 b4 = ((const float4*)(lnb + sub * 32))[j];
    float y0 = (v[j * 4 + 0] - mu) * rs * w4.x + b4.x;
    float y1 = (v[j * 4 + 1] - mu) * rs * w4.y + b4.y;
    float y2 = (v[j * 4 + 2] - mu) * rs * w4.z + b4.z;
    float y3 = (v[j * 4 + 3] - mu) * rs * w4.w + b4.w;
    float4 o4 = {y0, y1, y2, y3};
    ((float4*)xo)[j] = o4;
    bf16x4 ob;
    ob[0] = (bf16_t)y0; ob[1] = (bf16_t)y1; ob[2] = (bf16_t)y2; ob[3] = (bf16_t)y3;
    ((bf16x4*)xbo)[j] = ob;
  }
}

// ---------------- sparse attention v2: 4 rows/block, one wave per row ----------------
__global__ __launch_bounds__(256) void k_attn2(
    const float* __restrict__ qf, const bf16_t* __restrict__ kvb,
    const int* __restrict__ nbcol, const float* __restrict__ nbval,
    const int* __restrict__ nbcnt, bf16_t* __restrict__ aob) {
  const int w = threadIdx.x >> 6;
  const int l = threadIdx.x & 63;
  const int row = blockIdx.x * 4 + w;
  const int b = row >> 10;
  __shared__ float s_s[4][8][97];
  __shared__ int   s_col[4][CAP];
  __shared__ float s_bias[4][CAP];
  __shared__ float s_den[4][8];
  const int deg = nbcnt[row];
  for (int j = l; j < deg; j += 64) {
    s_col[w][j] = nbcol[(size_t)row * CAP + j];
    s_bias[w][j] = nbval[(size_t)row * CAP + j];
  }
  const int h1 = l & 7;
  float q[32];
  {
    const float4* qp = (const float4*)(qf + (size_t)row * 256 + h1 * 32);
#pragma unroll
    for (int u = 0; u < 8; ++u) {
      float4 t4 = qp[u];
      q[u * 4 + 0] = t4.x; q[u * 4 + 1] = t4.y; q[u * 4 + 2] = t4.z; q[u * 4 + 3] = t4.w;
    }
  }
  __syncthreads();

  const float scale = 0.17677669529663687f;   // 1/sqrt(32)
  const int nit = (deg + 7) >> 3;
  float mx = -INFINITY;
  for (int it = 0; it < nit; ++it) {
    int idx = it * 8 + (l >> 3);
    float sc = -INFINITY;
    if (idx < deg) {
      int col = s_col[w][idx];
      const bf16x8* kr = (const bf16x8*)(kvb + ((size_t)((b << 10) + col)) * 512 + h1 * 32);
      float d = 0.f;
#pragma unroll
      for (int u = 0; u < 4; ++u) {
        bf16x8 kv = kr[u];
#pragma unroll
        for (int j = 0; j < 8; ++j) d += (float)kv[j] * q[u * 8 + j];
      }
      sc = d * scale + s_bias[w][idx];
      s_s[w][h1][idx] = sc;
    }
    mx = fmaxf(mx, sc);
  }
#pragma unroll
  for (int o = 8; o < 64; o <<= 1) mx = fmaxf(mx, __shfl_xor(mx, o));
  __syncthreads();
  float lsum = 0.f;
  for (int it = 0; it < nit; ++it) {
    int idx = it * 8 + (l >> 3);
    if (idx < deg) {
      float p = __expf(s_s[w][h1][idx] - mx);
      s_s[w][h1][idx] = p;
      lsum += p;
    }
  }
#pragma unroll
  for (int o = 8; o < 64; o <<= 1) lsum += __shfl_xor(lsum, o);
  if (l < 8) s_den[w][l] = lsum;
  __syncthreads();
  const int h3 = l >> 3;
  float a0 = 0.f, a1 = 0.f, a2 = 0.f, a3 = 0.f;
  const bf16_t* vbase = kvb + ((size_t)(b << 10)) * 512 + 256 + l * 4;
#pragma unroll 4
  for (int idx = 0; idx < deg; ++idx) {
    float p = s_s[w][h3][idx];
    bf16x4 vv = *(const bf16x4*)(vbase + (size_t)s_col[w][idx] * 512);
    a0 += p * (float)vv[0]; a1 += p * (float)vv[1];
    a2 += p * (float)vv[2]; a3 += p * (float)vv[3];
  }
  float rden = 1.f / s_den[w][h3];
  bf16x4 o;
  o[0] = (bf16_t)(a0 * rden); o[1] = (bf16_t)(a1 * rden);
  o[2] = (bf16_t)(a2 * rden); o[3] = (bf16_t)(a3 * rden);
  *(bf16x4*)(aob + (size_t)row * 256 + l * 4) = o;
}

// ---------------- final LayerNorm (no residual), wave per row ----------------
__global__ __launch_bounds__(256) void k_ln(
    const float* __restrict__ xin,
    const float* __restrict__ w, const float* __restrict__ b,
    float* __restrict__ xout) {
  int r = blockIdx.x * 4 + (threadIdx.x >> 6);
  int l = threadIdx.x & 63;
  float4 v = ((const float4*)(xin + (size_t)r * 256))[l];
  float s = v.x + v.y + v.z + v.w;
#pragma unroll
  for (int o = 32; o; o >>= 1) s += __shfl_xor(s, o);
  float mu = s * (1.f / 256.f);
  float dx = v.x - mu, dy = v.y - mu, dz = v.z - mu, dw = v.w - mu;
  float e = dx * dx + dy * dy + dz * dz + dw * dw;
#pragma unroll
  for (int o = 32; o; o >>= 1) e += __shfl_xor(e, o);
  float rs = rsqrtf(e * (1.f / 256.f) + 1e-5f);
  float4 wv = ((const float4*)w)[l];
  float4 bv = ((const float4*)b)[l];
  float4 o4 = {dx * rs * wv.x + bv.x, dy * rs * wv.y + bv.y,
               dz * rs * wv.z + bv.z, dw * rs * wv.w + bv.w};
  ((float4*)(xout + (size_t)r * 256))[l] = o4;
}

extern "C" void kernel_launch(void* const* d_in, const int* in_sizes, int n_in,
                              void* d_out, int out_size, void* d_ws, size_t ws_size,
                              hipStream_t stream) {
  const float* H    = (const float*)d_in[0];
  const int*   ei   = (const int*)d_in[1];
  const float* m    = (const float*)d_in[2];
  const float* Wqkv = (const float*)d_in[3];
  const float* bqkv = (const float*)d_in[4];
  const float* Wo   = (const float*)d_in[5];
  const float* bo   = (const float*)d_in[6];
  const float* ln1w = (const float*)d_in[7];
  const float* ln1b = (const float*)d_in[8];
  const float* W1   = (const float*)d_in[9];
  const float* b1   = (const float*)d_in[10];
  const float* W2   = (const float*)d_in[11];
  const float* b2   = (const float*)d_in[12];
  const float* ln2w = (const float*)d_in[13];
  const float* ln2b = (const float*)d_in[14];
  const float* lnfw = (const float*)d_in[15];
  const float* lnfb = (const float*)d_in[16];

  char* ws = (char*)d_ws;
  size_t off = 0;
  auto alloc = [&](size_t bytes) {
    void* p = ws + off;
    off += (bytes + 255) & ~(size_t)255;
    return p;
  };

  // prio (32MB) reused later as qf (8MB) + kvb (8MB): prio dead after k_build_csr
  int*    prio  = (int*)alloc((size_t)BATCH * NTOK * NTOK * 4);
  float*  qf    = (float*)prio;                                     // [8192][256] f32
  bf16_t* kvb   = (bf16_t*)((char*)prio + (size_t)8 * 1024 * 1024); // [8192][512] bf16
  int*    nbcol = (int*)alloc((size_t)BATCH * NTOK * CAP * 4);
  float*  nbval = (float*)alloc((size_t)BATCH * NTOK * CAP * 4);
  int*    nbcnt = (int*)alloc((size_t)BATCH * NTOK * 4);
  bf16_t* wqkvb = (bf16_t*)alloc((size_t)2 * 768 * 256 * 2);
  bf16_t* wob   = (bf16_t*)alloc((size_t)2 * 256 * 256 * 2);
  bf16_t* w1b   = (bf16_t*)alloc((size_t)2 * 1024 * 256 * 2);
  bf16_t* w2b   = (bf16_t*)alloc((size_t)2 * 256 * 1024 * 2);
  bf16_t* xb    = (bf16_t*)alloc((size_t)8192 * 256 * 2);
  bf16_t* aob   = (bf16_t*)alloc((size_t)8192 * 256 * 2);
  bf16_t* ffb   = (bf16_t*)alloc((size_t)8192 * 1024 * 2);
  float*  xfA   = (float*)alloc((size_t)8192 * 256 * 4);
  float*  xfB   = (float*)alloc((size_t)8192 * 256 * 4);

  k_pre<<<5632, 256, 0, stream>>>(( int4*)prio, H, Wqkv, Wo, W1, W2,
                                  xb, wqkvb, wob, w1b, w2b);
  k_scatter<<<(BATCH * NEDGE + 255) / 256, 256, 0, stream>>>(ei, prio);
  k_build_csr<<<BATCH * NTOK / 4, 256, 0, stream>>>(prio, m, nbcol, nbval, nbcnt);

  const float* r1[2] = {H, xfB};    // residual input to ln1 per layer
  for (int lyr = 0; lyr < 2; ++lyr) {
    gemm_bt<2><<<dim3(768 / 128, 8192 / 128), 256, 0, stream>>>(
        xb, wqkvb + (size_t)lyr * 768 * 256, bqkv + lyr * 768, qf, kvb, 8192, 768, 256);
    k_attn2<<<BATCH * NTOK / 4, 256, 0, stream>>>(qf, kvb, nbcol, nbval, nbcnt, aob);
    gemm_ln<<<256, 256, 0, stream>>>(
        aob, wob + (size_t)lyr * 256 * 256, bo + lyr * 256, r1[lyr],
        ln1w + lyr * 256, ln1b + lyr * 256, xfA, xb, 256);
    gemm_bt<1><<<dim3(1024 / 128, 8192 / 128), 256, 0, stream>>>(
        xb, w1b + (size_t)lyr * 1024 * 256, b1 + lyr * 1024, nullptr, ffb, 8192, 1024, 256);
    gemm_ln<<<256, 256, 0, stream>>>(
        ffb, w2b + (size_t)lyr * 256 * 1024, b2 + lyr * 256, xfA,
        ln2w + lyr * 256, ln2b + lyr * 256, xfB, xb, 1024);
  }
  k_ln<<<8192 / 4, 256, 0, stream>>>(xfB, lnfw, lnfb, (float*)d_out);
}

// Round 5
// 233.556 us; speedup vs baseline: 1.0632x; 1.0632x over previous
//
#include <hip/hip_runtime.h>
#include <hip/hip_bf16.h>
#include <math.h>

typedef __bf16 bf16_t;
typedef __attribute__((ext_vector_type(8))) __bf16 bf16x8;
typedef __attribute__((ext_vector_type(4))) __bf16 bf16x4;
typedef __attribute__((ext_vector_type(4))) float f32x4;

#define BATCH 8
#define NTOK 1024
#define NEDGE 16384
#define CAP 96   // max neighbors per row (deg ~ Poisson(32); P(deg>96) < 1e-20)

// ---------------- async global->LDS (16B per lane, wave-uniform LDS base) ----------------
__device__ __forceinline__ void gload_lds16(const void* g, void* l) {
  __builtin_amdgcn_global_load_lds(
      (const __attribute__((address_space(1))) unsigned int*)(uintptr_t)g,
      (__attribute__((address_space(3))) unsigned int*)(unsigned int)(uintptr_t)l,
      16, 0, 0);
}

// ---------------- fused: zero prio (blocks 0..2047) + f32->bf16 cvt (blocks 2048..5631) ----------------
__global__ void k_pre(int4* __restrict__ prio,
                      const float* __restrict__ H, const float* __restrict__ Wqkv,
                      const float* __restrict__ Wo, const float* __restrict__ W1,
                      const float* __restrict__ W2, bf16_t* __restrict__ xb,
                      bf16_t* __restrict__ wqkvb, bf16_t* __restrict__ wob,
                      bf16_t* __restrict__ w1b, bf16_t* __restrict__ w2b) {
  if (blockIdx.x < 2048) {
    int i = blockIdx.x * 256 + threadIdx.x;
    int4 z = {0, 0, 0, 0};
#pragma unroll
    for (int u = 0; u < 4; ++u) prio[i + u * 524288] = z;   // 4 x 524288 int4 = 32MB
    return;
  }
  int i = (blockIdx.x - 2048) * 256 + threadIdx.x;   // float4-quad index
  const float* s; bf16_t* d; int off;
  if (i < 524288)      { s = H;    d = xb;    off = i; }
  else if (i < 622592) { s = Wqkv; d = wqkvb; off = i - 524288; }
  else if (i < 655360) { s = Wo;   d = wob;   off = i - 622592; }
  else if (i < 786432) { s = W1;   d = w1b;   off = i - 655360; }
  else if (i < 917504) { s = W2;   d = w2b;   off = i - 786432; }
  else return;
  float4 v = ((const float4*)s)[off];
  bf16x4 o;
  o[0] = (bf16_t)v.x; o[1] = (bf16_t)v.y; o[2] = (bf16_t)v.z; o[3] = (bf16_t)v.w;
  ((bf16x4*)d)[off] = o;
}

// ---------------- bias scatter: priority = scatter order (last write wins) ----------------
__global__ void k_scatter(const int* __restrict__ ei, int* __restrict__ prio) {
  int idx = blockIdx.x * 256 + threadIdx.x;
  if (idx >= BATCH * NEDGE) return;
  int b = idx >> 14;
  int e = idx & (NEDGE - 1);
  const int* eb = ei + (size_t)b * 2 * NEDGE;
  int r = eb[e], c = eb[NEDGE + e];
  int base = b << 20;
  atomicMax(prio + base + (r << 10) + c, e + 1);           // first scatter set
  atomicMax(prio + base + (c << 10) + r, NEDGE + e + 1);   // second scatter set (wins)
}

// ---------------- CSR build: one wave per row, deterministic ballot compaction ----------------
__global__ __launch_bounds__(256) void k_build_csr(
    const int* __restrict__ prio, const float* __restrict__ mptr,
    int* __restrict__ nbcol, float* __restrict__ nbval, int* __restrict__ nbcnt) {
  int row = blockIdx.x * 4 + (threadIdx.x >> 6);   // b*1024 + i
  int l = threadIdx.x & 63;
  int i = row & 1023;
  int b = row >> 10;
  int base = 0;
  for (int it = 0; it < 16; ++it) {
    int j = it * 64 + l;
    int p = prio[((size_t)row << 10) + j];
    bool hit = (p > 0) || (j == i);
    unsigned long long mask = __ballot(hit);
    int pos = base + __popcll(mask & ((1ull << l) - 1ull));
    if (hit && pos < CAP) {
      float v = 0.f;
      if (p > 0) {
        int e = (p - 1) & (NEDGE - 1);
        v = logf(mptr[(size_t)b * NEDGE + e] + 1e-9f);
      }
      nbcol[(size_t)row * CAP + pos] = j;
      nbval[(size_t)row * CAP + pos] = v;
    }
    base += __popcll(mask);
  }
  if (l == 0) nbcnt[row] = min(base, CAP);
}

// ---------------- GEMM 128x128: C[M,N] = A[M,K] * B[N,K]^T + bias ----------------
// EPI 1: gelu -> bf16 out. EPI 3: plain bf16 out.
template <int EPI>
__global__ __launch_bounds__(256) void gemm_bt(
    const bf16_t* __restrict__ A, const bf16_t* __restrict__ Bw,
    const float* __restrict__ bias, bf16_t* __restrict__ Cb,
    int M, int N, int K) {
  __shared__ bf16_t As[128 * 64];
  __shared__ bf16_t Bs[128 * 64];
  const int t = threadIdx.x;
  const int l = t & 63;
  const int w = t >> 6;
  const int wr = w >> 1, wc = w & 1;
  const int bm = blockIdx.y * 128, bn = blockIdx.x * 128;

  f32x4 acc[4][4] = {};

  for (int k0 = 0; k0 < K; k0 += 64) {
#pragma unroll
    for (int i = 0; i < 4; ++i) {
      int idx = i * 2048 + t * 8;
      int row = idx >> 6;
      int col = idx & 63;
      gload_lds16(A + (size_t)(bm + row) * K + (k0 + col), (void*)(As + i * 2048 + w * 512));
      gload_lds16(Bw + (size_t)(bn + row) * K + (k0 + col), (void*)(Bs + i * 2048 + w * 512));
    }
    asm volatile("s_waitcnt vmcnt(0)" ::: "memory");
    __syncthreads();
#pragma unroll
    for (int kk = 0; kk < 2; ++kk) {
      bf16x8 af[4], bfr[4];
#pragma unroll
      for (int mi = 0; mi < 4; ++mi)
        af[mi] = *(const bf16x8*)(As + (wr * 64 + mi * 16 + (l & 15)) * 64 + kk * 32 + (l >> 4) * 8);
#pragma unroll
      for (int ni = 0; ni < 4; ++ni)
        bfr[ni] = *(const bf16x8*)(Bs + (wc * 64 + ni * 16 + (l & 15)) * 64 + kk * 32 + (l >> 4) * 8);
#pragma unroll
      for (int mi = 0; mi < 4; ++mi)
#pragma unroll
        for (int ni = 0; ni < 4; ++ni)
          acc[mi][ni] = __builtin_amdgcn_mfma_f32_16x16x32_bf16(af[mi], bfr[ni], acc[mi][ni], 0, 0, 0);
    }
    __syncthreads();
  }

  const int r0 = (l >> 4) * 4;   // C/D: row=(lane>>4)*4+reg, col=lane&15
  const int cc = l & 15;
#pragma unroll
  for (int mi = 0; mi < 4; ++mi) {
#pragma unroll
    for (int ni = 0; ni < 4; ++ni) {
      int col = bn + wc * 64 + ni * 16 + cc;
      float bv = bias[col];
#pragma unroll
      for (int r = 0; r < 4; ++r) {
        int row = bm + wr * 64 + mi * 16 + r0 + r;
        float v = acc[mi][ni][r] + bv;
        if (EPI == 1)
          v = 0.5f * v * (1.f + erff(v * 0.70710678118654752f));   // exact GELU
        Cb[(size_t)row * N + col] = (bf16_t)v;
      }
    }
  }
}

// ---------------- fused GEMM(BM=16, BN=256) + bias + residual + LayerNorm ----------------
// y = LN(resid + A@Bw^T + bias); grid = M/16 = 512 blocks (2/CU), 4 waves each.
__global__ __launch_bounds__(256) void gemm_ln(
    const bf16_t* __restrict__ A, const bf16_t* __restrict__ Bw,
    const float* __restrict__ bias, const float* __restrict__ resid,
    const float* __restrict__ lnw, const float* __restrict__ lnb,
    float* __restrict__ xfout, bf16_t* __restrict__ xbout, int K) {
  __shared__ __align__(16) char smem[34816];
  bf16_t* As = (bf16_t*)smem;             // [16][64] = 2KB
  bf16_t* Bs = (bf16_t*)(smem + 2048);    // [256][64] = 32KB
  float*  E  = (float*)smem;              // epi: [16][258] f32 (aliases, after barrier)
  const int t = threadIdx.x;
  const int l = t & 63;
  const int w = t >> 6;
  const int bm = blockIdx.x * 16;

  f32x4 acc[4] = {};

  for (int k0 = 0; k0 < K; k0 += 64) {
    if (w < 2) {   // A tile 16x64: waves 0,1 stage 8 rows each
      int row = w * 8 + (l >> 3), col = (l & 7) * 8;
      gload_lds16(A + (size_t)(bm + row) * K + (k0 + col), (void*)(As + w * 512));
    }
#pragma unroll
    for (int i = 0; i < 8; ++i) {   // B tile 256x64: 8 issues per wave
      int rr = (w * 8 + i) * 8 + (l >> 3), col = (l & 7) * 8;
      gload_lds16(Bw + (size_t)rr * K + (k0 + col), (void*)(Bs + (w * 8 + i) * 512));
    }
    asm volatile("s_waitcnt vmcnt(0)" ::: "memory");
    __syncthreads();
#pragma unroll
    for (int kk = 0; kk < 2; ++kk) {
      bf16x8 af = *(const bf16x8*)(As + (l & 15) * 64 + kk * 32 + (l >> 4) * 8);
#pragma unroll
      for (int ni = 0; ni < 4; ++ni) {
        bf16x8 bfr = *(const bf16x8*)(Bs + (w * 64 + ni * 16 + (l & 15)) * 64 + kk * 32 + (l >> 4) * 8);
        acc[ni] = __builtin_amdgcn_mfma_f32_16x16x32_bf16(af, bfr, acc[ni], 0, 0, 0);
      }
    }
    __syncthreads();
  }

  // stash C+bias into LDS f32 [16][258]
  const int r0 = (l >> 4) * 4;
  const int cc = l & 15;
#pragma unroll
  for (int ni = 0; ni < 4; ++ni) {
    int col = w * 64 + ni * 16 + cc;
    float bv = bias[col];
#pragma unroll
    for (int r = 0; r < 4; ++r)
      E[(r0 + r) * 258 + col] = acc[ni][r] + bv;
  }
  __syncthreads();

  // LN: 16 threads per row, 16 cols per thread
  const int row = t >> 4;
  const int sub = t & 15;
  const float* ep = E + row * 258 + sub * 16;
  const float* rp = resid + (size_t)(bm + row) * 256 + sub * 16;
  float v[16];
  float s = 0.f;
#pragma unroll
  for (int j = 0; j < 4; ++j) {
    float4 a4 = ((const float4*)ep)[j];
    float4 b4 = ((const float4*)rp)[j];
    v[j * 4 + 0] = a4.x + b4.x; v[j * 4 + 1] = a4.y + b4.y;
    v[j * 4 + 2] = a4.z + b4.z; v[j * 4 + 3] = a4.w + b4.w;
    s += v[j * 4 + 0] + v[j * 4 + 1] + v[j * 4 + 2] + v[j * 4 + 3];
  }
#pragma unroll
  for (int o = 1; o < 16; o <<= 1) s += __shfl_xor(s, o);
  float mu = s * (1.f / 256.f);
  float e2 = 0.f;
#pragma unroll
  for (int j = 0; j < 16; ++j) { float d = v[j] - mu; e2 += d * d; }
#pragma unroll
  for (int o = 1; o < 16; o <<= 1) e2 += __shfl_xor(e2, o);
  float rs = rsqrtf(e2 * (1.f / 256.f) + 1e-5f);
  float* xo = xfout + (size_t)(bm + row) * 256 + sub * 16;
  bf16_t* xbo = xbout + (size_t)(bm + row) * 256 + sub * 16;
#pragma unroll
  for (int j = 0; j < 4; ++j) {
    float4 w4 = ((const float4*)(lnw + sub * 16))[j];
    float4 b4 = ((const float4*)(lnb + sub * 16))[j];
    float y0 = (v[j * 4 + 0] - mu) * rs * w4.x + b4.x;
    float y1 = (v[j * 4 + 1] - mu) * rs * w4.y + b4.y;
    float y2 = (v[j * 4 + 2] - mu) * rs * w4.z + b4.z;
    float y3 = (v[j * 4 + 3] - mu) * rs * w4.w + b4.w;
    float4 o4 = {y0, y1, y2, y3};
    ((float4*)xo)[j] = o4;
    bf16x4 ob;
    ob[0] = (bf16_t)y0; ob[1] = (bf16_t)y1; ob[2] = (bf16_t)y2; ob[3] = (bf16_t)y3;
    ((bf16x4*)xbo)[j] = ob;
  }
}

// ---------------- sparse attention: 4 rows/block, one wave per row, all-bf16 qkv ----------------
// qkvb layout: [8192][768] bf16 — q cols 0..255, k 256..511, v 512..767
__global__ __launch_bounds__(256) void k_attn2(
    const bf16_t* __restrict__ qkvb,
    const int* __restrict__ nbcol, const float* __restrict__ nbval,
    const int* __restrict__ nbcnt, bf16_t* __restrict__ aob) {
  const int w = threadIdx.x >> 6;
  const int l = threadIdx.x & 63;
  const int row = blockIdx.x * 4 + w;
  const int b = row >> 10;
  __shared__ float s_s[4][8][97];     // padded: conflict-free ph3
  __shared__ int   s_col[4][CAP];
  __shared__ float s_bias[4][CAP];
  __shared__ float s_den[4][8];
  const int deg = nbcnt[row];
  for (int j = l; j < deg; j += 64) {
    s_col[w][j] = nbcol[(size_t)row * CAP + j];
    s_bias[w][j] = nbval[(size_t)row * CAP + j];
  }
  const int h1 = l & 7;
  float q[32];
  {
    const bf16x8* qp = (const bf16x8*)(qkvb + (size_t)row * 768 + h1 * 32);
#pragma unroll
    for (int u = 0; u < 4; ++u) {
      bf16x8 t8 = qp[u];
#pragma unroll
      for (int j = 0; j < 8; ++j) q[u * 8 + j] = (float)t8[j];
    }
  }
  __syncthreads();

  const float scale = 0.17677669529663687f;   // 1/sqrt(32)
  const int nit = (deg + 7) >> 3;
  // phase 1: scores (8 nbrs x 8 heads per iter)
  float mx = -INFINITY;
  for (int it = 0; it < nit; ++it) {
    int idx = it * 8 + (l >> 3);
    float sc = -INFINITY;
    if (idx < deg) {
      int col = s_col[w][idx];
      const bf16x8* kr = (const bf16x8*)(qkvb + ((size_t)((b << 10) + col)) * 768 + 256 + h1 * 32);
      float d = 0.f;
#pragma unroll
      for (int u = 0; u < 4; ++u) {
        bf16x8 kv = kr[u];
#pragma unroll
        for (int j = 0; j < 8; ++j) d += (float)kv[j] * q[u * 8 + j];
      }
      sc = d * scale + s_bias[w][idx];
      s_s[w][h1][idx] = sc;
    }
    mx = fmaxf(mx, sc);
  }
#pragma unroll
  for (int o = 8; o < 64; o <<= 1) mx = fmaxf(mx, __shfl_xor(mx, o));
  __syncthreads();
  // phase 2: exp + denom
  float lsum = 0.f;
  for (int it = 0; it < nit; ++it) {
    int idx = it * 8 + (l >> 3);
    if (idx < deg) {
      float p = __expf(s_s[w][h1][idx] - mx);
      s_s[w][h1][idx] = p;
      lsum += p;
    }
  }
#pragma unroll
  for (int o = 8; o < 64; o <<= 1) lsum += __shfl_xor(lsum, o);
  if (l < 8) s_den[w][l] = lsum;
  __syncthreads();
  // phase 3: PV — all 64 lanes read one full V row per neighbor
  const int h3 = l >> 3;
  float a0 = 0.f, a1 = 0.f, a2 = 0.f, a3 = 0.f;
  const bf16_t* vbase = qkvb + ((size_t)(b << 10)) * 768 + 512 + l * 4;
#pragma unroll 4
  for (int idx = 0; idx < deg; ++idx) {
    float p = s_s[w][h3][idx];
    bf16x4 vv = *(const bf16x4*)(vbase + (size_t)s_col[w][idx] * 768);
    a0 += p * (float)vv[0]; a1 += p * (float)vv[1];
    a2 += p * (float)vv[2]; a3 += p * (float)vv[3];
  }
  float rden = 1.f / s_den[w][h3];
  bf16x4 o;
  o[0] = (bf16_t)(a0 * rden); o[1] = (bf16_t)(a1 * rden);
  o[2] = (bf16_t)(a2 * rden); o[3] = (bf16_t)(a3 * rden);
  *(bf16x4*)(aob + (size_t)row * 256 + l * 4) = o;
}

// ---------------- final LayerNorm (no residual), wave per row ----------------
__global__ __launch_bounds__(256) void k_ln(
    const float* __restrict__ xin,
    const float* __restrict__ w, const float* __restrict__ b,
    float* __restrict__ xout) {
  int r = blockIdx.x * 4 + (threadIdx.x >> 6);
  int l = threadIdx.x & 63;
  float4 v = ((const float4*)(xin + (size_t)r * 256))[l];
  float s = v.x + v.y + v.z + v.w;
#pragma unroll
  for (int o = 32; o; o >>= 1) s += __shfl_xor(s, o);
  float mu = s * (1.f / 256.f);
  float dx = v.x - mu, dy = v.y - mu, dz = v.z - mu, dw = v.w - mu;
  float e = dx * dx + dy * dy + dz * dz + dw * dw;
#pragma unroll
  for (int o = 32; o; o >>= 1) e += __shfl_xor(e, o);
  float rs = rsqrtf(e * (1.f / 256.f) + 1e-5f);
  float4 wv = ((const float4*)w)[l];
  float4 bv = ((const float4*)b)[l];
  float4 o4 = {dx * rs * wv.x + bv.x, dy * rs * wv.y + bv.y,
               dz * rs * wv.z + bv.z, dw * rs * wv.w + bv.w};
  ((float4*)(xout + (size_t)r * 256))[l] = o4;
}

extern "C" void kernel_launch(void* const* d_in, const int* in_sizes, int n_in,
                              void* d_out, int out_size, void* d_ws, size_t ws_size,
                              hipStream_t stream) {
  const float* H    = (const float*)d_in[0];
  const int*   ei   = (const int*)d_in[1];
  const float* m    = (const float*)d_in[2];
  const float* Wqkv = (const float*)d_in[3];
  const float* bqkv = (const float*)d_in[4];
  const float* Wo   = (const float*)d_in[5];
  const float* bo   = (const float*)d_in[6];
  const float* ln1w = (const float*)d_in[7];
  const float* ln1b = (const float*)d_in[8];
  const float* W1   = (const float*)d_in[9];
  const float* b1   = (const float*)d_in[10];
  const float* W2   = (const float*)d_in[11];
  const float* b2   = (const float*)d_in[12];
  const float* ln2w = (const float*)d_in[13];
  const float* ln2b = (const float*)d_in[14];
  const float* lnfw = (const float*)d_in[15];
  const float* lnfb = (const float*)d_in[16];

  char* ws = (char*)d_ws;
  size_t off = 0;
  auto alloc = [&](size_t bytes) {
    void* p = ws + off;
    off += (bytes + 255) & ~(size_t)255;
    return p;
  };

  // prio (32MB) reused later as qkvb (12MB): prio dead after k_build_csr
  int*    prio  = (int*)alloc((size_t)BATCH * NTOK * NTOK * 4);
  bf16_t* qkvb  = (bf16_t*)prio;                 // [8192][768] bf16
  int*    nbcol = (int*)alloc((size_t)BATCH * NTOK * CAP * 4);
  float*  nbval = (float*)alloc((size_t)BATCH * NTOK * CAP * 4);
  int*    nbcnt = (int*)alloc((size_t)BATCH * NTOK * 4);
  bf16_t* wqkvb = (bf16_t*)alloc((size_t)2 * 768 * 256 * 2);
  bf16_t* wob   = (bf16_t*)alloc((size_t)2 * 256 * 256 * 2);
  bf16_t* w1b   = (bf16_t*)alloc((size_t)2 * 1024 * 256 * 2);
  bf16_t* w2b   = (bf16_t*)alloc((size_t)2 * 256 * 1024 * 2);
  bf16_t* xb    = (bf16_t*)alloc((size_t)8192 * 256 * 2);
  bf16_t* aob   = (bf16_t*)alloc((size_t)8192 * 256 * 2);
  bf16_t* ffb   = (bf16_t*)alloc((size_t)8192 * 1024 * 2);
  float*  xfA   = (float*)alloc((size_t)8192 * 256 * 4);
  float*  xfB   = (float*)alloc((size_t)8192 * 256 * 4);

  k_pre<<<5632, 256, 0, stream>>>((int4*)prio, H, Wqkv, Wo, W1, W2,
                                  xb, wqkvb, wob, w1b, w2b);
  k_scatter<<<(BATCH * NEDGE + 255) / 256, 256, 0, stream>>>(ei, prio);
  k_build_csr<<<BATCH * NTOK / 4, 256, 0, stream>>>(prio, m, nbcol, nbval, nbcnt);

  const float* r1[2] = {H, xfB};    // residual input to ln1 per layer
  for (int lyr = 0; lyr < 2; ++lyr) {
    gemm_bt<3><<<dim3(768 / 128, 8192 / 128), 256, 0, stream>>>(
        xb, wqkvb + (size_t)lyr * 768 * 256, bqkv + lyr * 768, qkvb, 8192, 768, 256);
    k_attn2<<<BATCH * NTOK / 4, 256, 0, stream>>>(qkvb, nbcol, nbval, nbcnt, aob);
    gemm_ln<<<512, 256, 0, stream>>>(
        aob, wob + (size_t)lyr * 256 * 256, bo + lyr * 256, r1[lyr],
        ln1w + lyr * 256, ln1b + lyr * 256, xfA, xb, 256);
    gemm_bt<1><<<dim3(1024 / 128, 8192 / 128), 256, 0, stream>>>(
        xb, w1b + (size_t)lyr * 1024 * 256, b1 + lyr * 1024, ffb, 8192, 1024, 256);
    gemm_ln<<<512, 256, 0, stream>>>(
        ffb, w2b + (size_t)lyr * 256 * 1024, b2 + lyr * 256, xfA,
        ln2w + lyr * 256, ln2b + lyr * 256, xfB, xb, 1024);
  }
  k_ln<<<8192 / 4, 256, 0, stream>>>(xfB, lnfw, lnfb, (float*)d_out);
}